// Round 12
// baseline (13.392 us; speedup 1.0000x reference)
//
#include <hip/hip_runtime.h>
#include <math.h>

namespace {

constexpr int BB = 8;
constexpr int NN = 1024;
constexpr int CC = 10;
constexpr float RADIUS = 0.04f;
constexpr float ACCEL_SCALE = 0.02f;
constexpr float MAX_VEL = 0.02f;
constexpr float MAX_POS = 1.0f;
constexpr float EPS = 1e-9f;
// superset prefilter: exact hit needs d2 < 0.0016; margin covers fma + ulps
constexpr float D2_PREFILTER = 0.0017f;

// ONE kernel, no workspace. grid = 256 blocks (8 batches x 32 chunks of 32
// rows) = exactly 1 block/CU -> all blocks co-resident in one dispatch round;
// per-block fixed costs (40KB staging, barriers, weight loads, reduce,
// epilogue) amortize over 2x the rows vs round 11. Block = 512 threads =
// 8 waves; wave w owns rows {4w..4w+3}. Hits are ballot-compacted; the hit
// body recomputes rel from the broadcast LDS read (bit-identical decisions).
// Per-lane h-slice weights (lane h = sub & 15); 4 replica groups hold
// bit-identical partials -> 4-step xor reduce within 16-lane groups is the
// exact full h-sum, and afterwards EVERY lane holds all 4 rows' sums.
__global__ __launch_bounds__(512) void gnca_one(
    const float* __restrict__ x,   // (B, N, 10)
    const float* __restrict__ W1,  // (14, 16) row-major
    const float* __restrict__ b1,  // (16,)
    const float* __restrict__ W2,  // (16, 7) row-major
    const float* __restrict__ b2,  // (7,)
    float* __restrict__ out)       // (B, N, 10)
{
    __shared__ alignas(16) float2 raw2[NN * 5];   // 40 KB: x[b] row-major
    __shared__ alignas(16) float2 pos2[NN];       // 8 KB

    const int tid = threadIdx.x;
    const int blk = blockIdx.x;          // 0..255
    const int b = blk >> 5;              // batch
    const int row0 = (blk & 31) * 32;    // 32 i-rows per block
    const int w   = tid >> 6;            // wave 0..7
    const int sub = tid & 63;            // 0..63
    const int hh  = sub & 15;            // this lane's h-slice

    // per-lane h-slice weights (vector loads, issued early, L2-resident)
    const float b1h = b1[hh];
    const float w1d = W1[hh];
    const float w1x = W1[16 + hh];
    const float w1y = W1[32 + hh];
    const float w1t = W1[48 + hh];
    float w1c[CC];
#pragma unroll
    for (int c = 0; c < CC; ++c) w1c[c] = W1[(4 + c) * 16 + hh];
    const float w20 = W2[hh * 7 + 0];
    const float w21 = W2[hh * 7 + 1];

    const float* __restrict__ xb = x + (size_t)b * NN * CC;

    // ---- Phase A: coalesced copy of x[b] (40 KB) into LDS ----
    {
        const float4* __restrict__ src = (const float4*)xb;   // 2560 float4
        float4* __restrict__ dst = (float4*)raw2;
#pragma unroll
        for (int k = 0; k < 5; ++k) dst[k * 512 + tid] = src[k * 512 + tid];
    }
    __syncthreads();

    // ---- Phase B: extract pos2 (thread t -> nodes 2t, 2t+1) ----
    {
        const float4* __restrict__ r4 = (const float4*)raw2;
        const float4 r0 = r4[tid * 5 + 0];   // node 2t   ch 0..3
        const float4 r2 = r4[tid * 5 + 2];   // node 2t+1 ch 0,1 in .z,.w
        ((float4*)pos2)[tid] = make_float4(r0.x, r0.y, r2.z, r2.w);
    }
    __syncthreads();

    const int ibase = row0 + w * 4;      // wave's first row
    float2 pi[4];
#pragma unroll
    for (int r = 0; r < 4; ++r) pi[r] = pos2[ibase + r];   // wave-uniform

    float o0p[4] = {0.f, 0.f, 0.f, 0.f};
    float o1p[4] = {0.f, 0.f, 0.f, 0.f};
    float dgp[4] = {0.f, 0.f, 0.f, 0.f};
    float cnp[4] = {0.f, 0.f, 0.f, 0.f};

    for (int jj = 0; jj < 16; ++jj) {
        const float2 pj = pos2[(jj << 6) + sub];   // ds_read_b64, 2-way free

#pragma unroll
        for (int r = 0; r < 4; ++r) {
            const float dx = pj.x - pi[r].x;
            const float dy = pj.y - pi[r].y;
            unsigned long long m = __ballot(dx * dx + dy * dy < D2_PREFILTER);

            while (m) {
                const int src = __builtin_ctzll(m);
                m &= (m - 1);
                const int bj = (jj << 6) + src;          // wave-uniform
                const float2 q0 = raw2[bj * 5 + 0];      // broadcast reads,
                const float2 q1 = raw2[bj * 5 + 1];      // independent ->
                const float2 q2 = raw2[bj * 5 + 2];      // one lgkm wait
                const float2 q3 = raw2[bj * 5 + 3];
                const float2 q4 = raw2[bj * 5 + 4];
                // recompute rel in-register: same bits as the lane's dx,dy
                const float bx = q0.x - pi[r].x;
                const float by = q0.y - pi[r].y;
                // exact fp32 path: bit-identical to numpy boundary decisions
                const float d2 =
                    __fadd_rn(__fadd_rn(__fmul_rn(bx, bx), __fmul_rn(by, by)), EPS);
                const float dist = __fsqrt_rn(d2);
                if (dist < RADIUS) {                     // uniform across wave
                    const float tgt = q2.x;
                    float v = b1h;
                    v = fmaf(q0.x, w1c[0], v);  v = fmaf(q0.y, w1c[1], v);
                    v = fmaf(q1.x, w1c[2], v);  v = fmaf(q1.y, w1c[3], v);
                    v = fmaf(q2.x, w1c[4], v);  v = fmaf(q2.y, w1c[5], v);
                    v = fmaf(q3.x, w1c[6], v);  v = fmaf(q3.y, w1c[7], v);
                    v = fmaf(q4.x, w1c[8], v);  v = fmaf(q4.y, w1c[9], v);
                    v = fmaf(tgt,  w1t, v);
                    v = fmaf(by,   w1y, v);
                    v = fmaf(bx,   w1x, v);
                    v = fmaf(dist, w1d, v);
                    v = fmaxf(v, 0.0f);
                    o0p[r] = fmaf(v, w20, o0p[r]);
                    o1p[r] = fmaf(v, w21, o1p[r]);
                    dgp[r] += 1.0f;                      // uniform on all lanes
                    cnp[r] += (tgt > 0.5f) ? 1.0f : 0.0f;
                }
            }
        }
    }

    // 4-step reduce within 16-lane groups: replica groups are bit-identical,
    // so this equals the full 16-slice h-sum exactly. Every lane ends up
    // holding all 4 rows' reduced sums.
#pragma unroll
    for (int mm = 1; mm < 16; mm <<= 1) {
#pragma unroll
        for (int r = 0; r < 4; ++r) {
            o0p[r] += __shfl_xor(o0p[r], mm, 64);
            o1p[r] += __shfl_xor(o1p[r], mm, 64);
        }
    }

    // lanes 0..3 each finalize one row
    if (sub < 4) {
        float o0s = o0p[0], o1s = o1p[0], degs = dgp[0], cns = cnp[0];
        float2 pis = pi[0];
#pragma unroll
        for (int r = 1; r < 4; ++r) {   // static select by lane
            if (sub == r) {
                o0s = o0p[r]; o1s = o1p[r]; degs = dgp[r]; cns = cnp[r];
                pis = pi[r];
            }
        }
        const int iu = ibase + sub;

        const float2 q1 = raw2[iu * 5 + 1];   // vel
        const float2 q2 = raw2[iu * 5 + 2];   // typ, c5
        const float2 q3 = raw2[iu * 5 + 3];   // c6, c7
        const float2 q4 = raw2[iu * 5 + 4];   // c8, c9

        const float typ_i = q2.x;
        const bool is_cell = typ_i > 0.5f;

        float o0 = degs * b2[0] + o0s;
        float o1 = degs * b2[1] + o1s;
        if (!is_cell) { o0 = 0.0f; o1 = 0.0f; }

        float nvx = q1.x, nvy = q1.y;
        float npx = pis.x, npy = pis.y;
        if (is_cell) {
            nvx = fminf(fmaxf(q1.x + o0 * ACCEL_SCALE, -MAX_VEL), MAX_VEL);
            nvy = fminf(fmaxf(q1.y + o1 * ACCEL_SCALE, -MAX_VEL), MAX_VEL);
            npx = fminf(fmaxf(pis.x + nvx, -MAX_POS), MAX_POS);
            npy = fminf(fmaxf(pis.y + nvy, -MAX_POS), MAX_POS);
        }

        const bool dead     = is_cell && (degs < 3.0f);
        const bool consumed = (!is_cell) && (cns >= 1.0f);
        const float keep = (dead || consumed) ? 0.0f : 1.0f;

        float2* __restrict__ op2 = (float2*)(out + ((size_t)b * NN + iu) * CC);
        op2[0] = make_float2(npx * keep, npy * keep);
        op2[1] = make_float2(nvx * keep, nvy * keep);
        op2[2] = make_float2(typ_i * keep, q2.y * keep);
        op2[3] = make_float2(q3.x * keep, q3.y * keep);
        op2[4] = make_float2(q4.x * keep, q4.y * keep);
    }
}

}  // namespace

extern "C" void kernel_launch(void* const* d_in, const int* in_sizes, int n_in,
                              void* d_out, int out_size, void* d_ws, size_t ws_size,
                              hipStream_t stream) {
    const float* x  = (const float*)d_in[0];
    const float* W1 = (const float*)d_in[1];
    const float* b1 = (const float*)d_in[2];
    const float* W2 = (const float*)d_in[3];
    const float* b2 = (const float*)d_in[4];
    float* out = (float*)d_out;

    gnca_one<<<dim3(256), dim3(512), 0, stream>>>(x, W1, b1, W2, b2, out);
}

// Round 13
// 13.201 us; speedup vs baseline: 1.0144x; 1.0144x over previous
//
#include <hip/hip_runtime.h>
#include <math.h>

namespace {

constexpr int BB = 8;
constexpr int NN = 1024;
constexpr int CC = 10;
constexpr float RADIUS = 0.04f;
constexpr float ACCEL_SCALE = 0.02f;
constexpr float MAX_VEL = 0.02f;
constexpr float MAX_POS = 1.0f;
constexpr float EPS = 1e-9f;
// superset prefilter: exact hit needs d2 < 0.0016; margin covers fma + ulps
constexpr float D2_PREFILTER = 0.0017f;

// ONE kernel, no workspace. grid = 1024 blocks (8 batches x 128 chunks of 8
// rows), block = 512 threads = 8 waves, ONE row per wave (the ballot->while
// hit loop is serial per row, so rows/wave multiplies the critical path;
// round 9->12 showed fewer rows/wave monotonically wins). 48 KB LDS ->
// 3 blocks/CU co-resident -> ~24 waves/CU during the main dispatch round.
// Hits are ballot-compacted; hit body recomputes rel from the broadcast LDS
// read (bit-identical decisions). Per-lane h-slice weights (lane h=sub&15);
// the 4 replica groups hold bit-identical partials -> 4-step xor reduce
// within 16-lane groups is the exact full h-sum.
__global__ __launch_bounds__(512) void gnca_one(
    const float* __restrict__ x,   // (B, N, 10)
    const float* __restrict__ W1,  // (14, 16) row-major
    const float* __restrict__ b1,  // (16,)
    const float* __restrict__ W2,  // (16, 7) row-major
    const float* __restrict__ b2,  // (7,)
    float* __restrict__ out)       // (B, N, 10)
{
    __shared__ alignas(16) float2 raw2[NN * 5];   // 40 KB: x[b] row-major
    __shared__ alignas(16) float2 pos2[NN];       // 8 KB

    const int tid = threadIdx.x;
    const int blk = blockIdx.x;          // 0..1023
    const int b = blk >> 7;              // batch
    const int row0 = (blk & 127) * 8;    // 8 i-rows per block
    const int w   = tid >> 6;            // wave 0..7
    const int sub = tid & 63;            // 0..63
    const int hh  = sub & 15;            // this lane's h-slice

    // per-lane h-slice weights (vector loads, issued early, L2-resident)
    const float b1h = b1[hh];
    const float w1d = W1[hh];
    const float w1x = W1[16 + hh];
    const float w1y = W1[32 + hh];
    const float w1t = W1[48 + hh];
    float w1c[CC];
#pragma unroll
    for (int c = 0; c < CC; ++c) w1c[c] = W1[(4 + c) * 16 + hh];
    const float w20 = W2[hh * 7 + 0];
    const float w21 = W2[hh * 7 + 1];

    const float* __restrict__ xb = x + (size_t)b * NN * CC;

    // ---- Phase A: coalesced copy of x[b] (40 KB) into LDS ----
    {
        const float4* __restrict__ src = (const float4*)xb;   // 2560 float4
        float4* __restrict__ dst = (float4*)raw2;
#pragma unroll
        for (int k = 0; k < 5; ++k) dst[k * 512 + tid] = src[k * 512 + tid];
    }
    __syncthreads();

    // ---- Phase B: extract pos2 (thread t -> nodes 2t, 2t+1) ----
    {
        const float4* __restrict__ r4 = (const float4*)raw2;
        const float4 r0 = r4[tid * 5 + 0];   // node 2t   ch 0..3
        const float4 r2 = r4[tid * 5 + 2];   // node 2t+1 ch 0,1 in .z,.w
        ((float4*)pos2)[tid] = make_float4(r0.x, r0.y, r2.z, r2.w);
    }
    __syncthreads();

    const int iu = row0 + w;             // this wave's row
    const float2 pi = pos2[iu];          // wave-uniform -> broadcast

    float o0p = 0.0f, o1p = 0.0f, dg = 0.0f, cn = 0.0f;

#pragma unroll
    for (int g = 0; g < 2; ++g) {
        // batched position loads: 8 ds_read_b64 in flight, one wait
        float2 pjv[8];
#pragma unroll
        for (int q = 0; q < 8; ++q)
            pjv[q] = pos2[(((g << 3) + q) << 6) + sub];

#pragma unroll
        for (int q = 0; q < 8; ++q) {
            const int jj = (g << 3) + q;
            const float2 pj = pjv[q];
            const float dx = pj.x - pi.x;
            const float dy = pj.y - pi.y;
            unsigned long long m = __ballot(dx * dx + dy * dy < D2_PREFILTER);

            while (m) {
                const int src = __builtin_ctzll(m);
                m &= (m - 1);
                const int bj = (jj << 6) + src;          // wave-uniform
                const float2 q0 = raw2[bj * 5 + 0];      // broadcast reads,
                const float2 q1 = raw2[bj * 5 + 1];      // independent ->
                const float2 q2 = raw2[bj * 5 + 2];      // one lgkm wait
                const float2 q3 = raw2[bj * 5 + 3];
                const float2 q4 = raw2[bj * 5 + 4];
                // recompute rel in-register: same bits as source lane's dx,dy
                const float bx = q0.x - pi.x;
                const float by = q0.y - pi.y;
                // exact fp32 path: bit-identical to numpy boundary decisions
                const float d2 =
                    __fadd_rn(__fadd_rn(__fmul_rn(bx, bx), __fmul_rn(by, by)), EPS);
                const float dist = __fsqrt_rn(d2);
                if (dist < RADIUS) {                     // uniform across wave
                    const float tgt = q2.x;
                    float v = b1h;
                    v = fmaf(q0.x, w1c[0], v);  v = fmaf(q0.y, w1c[1], v);
                    v = fmaf(q1.x, w1c[2], v);  v = fmaf(q1.y, w1c[3], v);
                    v = fmaf(q2.x, w1c[4], v);  v = fmaf(q2.y, w1c[5], v);
                    v = fmaf(q3.x, w1c[6], v);  v = fmaf(q3.y, w1c[7], v);
                    v = fmaf(q4.x, w1c[8], v);  v = fmaf(q4.y, w1c[9], v);
                    v = fmaf(tgt,  w1t, v);
                    v = fmaf(by,   w1y, v);
                    v = fmaf(bx,   w1x, v);
                    v = fmaf(dist, w1d, v);
                    v = fmaxf(v, 0.0f);
                    o0p = fmaf(v, w20, o0p);
                    o1p = fmaf(v, w21, o1p);
                    dg += 1.0f;                          // uniform on all lanes
                    cn += (tgt > 0.5f) ? 1.0f : 0.0f;
                }
            }
        }
    }

    // 4-step reduce within 16-lane groups: replica groups are bit-identical,
    // so this equals the full 16-slice h-sum exactly.
#pragma unroll
    for (int mm = 1; mm < 16; mm <<= 1) {
        o0p += __shfl_xor(o0p, mm, 64);
        o1p += __shfl_xor(o1p, mm, 64);
    }

    // lane 0 finalizes this wave's row
    if (sub == 0) {
        const float2 q1 = raw2[iu * 5 + 1];   // vel
        const float2 q2 = raw2[iu * 5 + 2];   // typ, c5
        const float2 q3 = raw2[iu * 5 + 3];   // c6, c7
        const float2 q4 = raw2[iu * 5 + 4];   // c8, c9

        const float typ_i = q2.x;
        const bool is_cell = typ_i > 0.5f;

        float o0 = dg * b2[0] + o0p;
        float o1 = dg * b2[1] + o1p;
        if (!is_cell) { o0 = 0.0f; o1 = 0.0f; }

        float nvx = q1.x, nvy = q1.y;
        float npx = pi.x, npy = pi.y;
        if (is_cell) {
            nvx = fminf(fmaxf(q1.x + o0 * ACCEL_SCALE, -MAX_VEL), MAX_VEL);
            nvy = fminf(fmaxf(q1.y + o1 * ACCEL_SCALE, -MAX_VEL), MAX_VEL);
            npx = fminf(fmaxf(pi.x + nvx, -MAX_POS), MAX_POS);
            npy = fminf(fmaxf(pi.y + nvy, -MAX_POS), MAX_POS);
        }

        const bool dead     = is_cell && (dg < 3.0f);
        const bool consumed = (!is_cell) && (cn >= 1.0f);
        const float keep = (dead || consumed) ? 0.0f : 1.0f;

        float2* __restrict__ op2 = (float2*)(out + ((size_t)b * NN + iu) * CC);
        op2[0] = make_float2(npx * keep, npy * keep);
        op2[1] = make_float2(nvx * keep, nvy * keep);
        op2[2] = make_float2(typ_i * keep, q2.y * keep);
        op2[3] = make_float2(q3.x * keep, q3.y * keep);
        op2[4] = make_float2(q4.x * keep, q4.y * keep);
    }
}

}  // namespace

extern "C" void kernel_launch(void* const* d_in, const int* in_sizes, int n_in,
                              void* d_out, int out_size, void* d_ws, size_t ws_size,
                              hipStream_t stream) {
    const float* x  = (const float*)d_in[0];
    const float* W1 = (const float*)d_in[1];
    const float* b1 = (const float*)d_in[2];
    const float* W2 = (const float*)d_in[3];
    const float* b2 = (const float*)d_in[4];
    float* out = (float*)d_out;

    gnca_one<<<dim3(BB * 128), dim3(512), 0, stream>>>(x, W1, b1, W2, b2, out);
}

// Round 14
// 11.684 us; speedup vs baseline: 1.1462x; 1.1299x over previous
//
#include <hip/hip_runtime.h>
#include <math.h>

namespace {

constexpr int BB = 8;
constexpr int NN = 1024;
constexpr int CC = 10;
constexpr float RADIUS = 0.04f;
constexpr float ACCEL_SCALE = 0.02f;
constexpr float MAX_VEL = 0.02f;
constexpr float MAX_POS = 1.0f;
constexpr float EPS = 1e-9f;
// superset prefilter: exact hit needs d2 < 0.0016; margin covers fma + ulps
constexpr float D2_PREFILTER = 0.0017f;

// ROUND-11 CONFIG (best measured: 11.7 us). grid = 512 blocks (8 batches x
// 64 chunks of 16 rows), block = 512 threads = 8 waves, 2 rows per wave.
// Occupancy sweep bracketed this as the optimum: 256 blk = 13.4us,
// 512 blk = 11.7us, 1024 blk = 13.2us.
// Hits are ballot-compacted. The hit body does NOT shfl-broadcast the rel
// vector (ds_bpermute, ~120cyc x2 serial); it recomputes it from the
// broadcast LDS read of the hit row's channels 0,1 (same bits, same ops ->
// bit-identical dist). Per-lane h-slice weights (lane h = sub & 15); the 4
// replica groups hold bit-identical partials, so a 4-step xor reduce within
// 16-lane groups yields the exact full h-sum.
__global__ __launch_bounds__(512, 4) void gnca_one(
    const float* __restrict__ x,   // (B, N, 10)
    const float* __restrict__ W1,  // (14, 16) row-major
    const float* __restrict__ b1,  // (16,)
    const float* __restrict__ W2,  // (16, 7) row-major
    const float* __restrict__ b2,  // (7,)
    float* __restrict__ out)       // (B, N, 10)
{
    __shared__ alignas(16) float2 raw2[NN * 5];   // 40 KB: x[b] row-major
    __shared__ alignas(16) float2 pos2[NN];       // 8 KB

    const int tid = threadIdx.x;
    const int blk = blockIdx.x;          // 0..511
    const int b = blk >> 6;              // batch
    const int row0 = (blk & 63) * 16;    // 16 i-rows per block
    const int w   = tid >> 6;            // wave 0..7
    const int sub = tid & 63;            // 0..63
    const int hh  = sub & 15;            // this lane's h-slice

    // per-lane h-slice weights (vector loads, issued early, L2-resident)
    const float b1h = b1[hh];
    const float w1d = W1[hh];
    const float w1x = W1[16 + hh];
    const float w1y = W1[32 + hh];
    const float w1t = W1[48 + hh];
    float w1c[CC];
#pragma unroll
    for (int c = 0; c < CC; ++c) w1c[c] = W1[(4 + c) * 16 + hh];
    const float w20 = W2[hh * 7 + 0];
    const float w21 = W2[hh * 7 + 1];

    const float* __restrict__ xb = x + (size_t)b * NN * CC;

    // ---- Phase A: coalesced copy of x[b] (40 KB) into LDS ----
    {
        const float4* __restrict__ src = (const float4*)xb;   // 2560 float4
        float4* __restrict__ dst = (float4*)raw2;
#pragma unroll
        for (int k = 0; k < 5; ++k) dst[k * 512 + tid] = src[k * 512 + tid];
    }
    __syncthreads();

    // ---- Phase B: extract pos2 (thread t -> nodes 2t, 2t+1) ----
    {
        const float4* __restrict__ r4 = (const float4*)raw2;
        const float4 r0 = r4[tid * 5 + 0];   // node 2t   ch 0..3
        const float4 r2 = r4[tid * 5 + 2];   // node 2t+1 ch 0,1 in .z,.w
        ((float4*)pos2)[tid] = make_float4(r0.x, r0.y, r2.z, r2.w);
    }
    __syncthreads();

    const int iu0 = row0 + w * 2;
    const int iu1 = iu0 + 1;
    const float2 pi0 = pos2[iu0];   // wave-uniform -> broadcast
    const float2 pi1 = pos2[iu1];

    float o0p_r0 = 0.0f, o1p_r0 = 0.0f, dg0 = 0.0f, cn0 = 0.0f;
    float o0p_r1 = 0.0f, o1p_r1 = 0.0f, dg1 = 0.0f, cn1 = 0.0f;

#pragma unroll
    for (int g = 0; g < 2; ++g) {
        // batched position loads: 8 ds_read_b64 in flight, one wait
        float2 pjv[8];
#pragma unroll
        for (int q = 0; q < 8; ++q)
            pjv[q] = pos2[(((g << 3) + q) << 6) + sub];

#pragma unroll
        for (int q = 0; q < 8; ++q) {
            const int jj = (g << 3) + q;
            const float2 pj = pjv[q];
            const float dx0 = pj.x - pi0.x, dy0 = pj.y - pi0.y;
            const float dx1 = pj.x - pi1.x, dy1 = pj.y - pi1.y;
            unsigned long long m0 = __ballot(dx0 * dx0 + dy0 * dy0 < D2_PREFILTER);
            unsigned long long m1 = __ballot(dx1 * dx1 + dy1 * dy1 < D2_PREFILTER);

            while (m0) {
                const int src = __builtin_ctzll(m0);
                m0 &= (m0 - 1);
                const int bj = (jj << 6) + src;          // wave-uniform
                const float2 q0 = raw2[bj * 5 + 0];      // broadcast reads,
                const float2 q1 = raw2[bj * 5 + 1];      // independent ->
                const float2 q2 = raw2[bj * 5 + 2];      // one lgkm wait
                const float2 q3 = raw2[bj * 5 + 3];
                const float2 q4 = raw2[bj * 5 + 4];
                // recompute rel in-register: same bits as source lane's dx,dy
                const float bx = q0.x - pi0.x;
                const float by = q0.y - pi0.y;
                // exact fp32 path: bit-identical to numpy boundary decisions
                const float d2 =
                    __fadd_rn(__fadd_rn(__fmul_rn(bx, bx), __fmul_rn(by, by)), EPS);
                const float dist = __fsqrt_rn(d2);
                if (dist < RADIUS) {                     // uniform across wave
                    const float tgt = q2.x;
                    float v = b1h;
                    v = fmaf(q0.x, w1c[0], v);  v = fmaf(q0.y, w1c[1], v);
                    v = fmaf(q1.x, w1c[2], v);  v = fmaf(q1.y, w1c[3], v);
                    v = fmaf(q2.x, w1c[4], v);  v = fmaf(q2.y, w1c[5], v);
                    v = fmaf(q3.x, w1c[6], v);  v = fmaf(q3.y, w1c[7], v);
                    v = fmaf(q4.x, w1c[8], v);  v = fmaf(q4.y, w1c[9], v);
                    v = fmaf(tgt,  w1t, v);
                    v = fmaf(by,   w1y, v);
                    v = fmaf(bx,   w1x, v);
                    v = fmaf(dist, w1d, v);
                    v = fmaxf(v, 0.0f);
                    o0p_r0 = fmaf(v, w20, o0p_r0);
                    o1p_r0 = fmaf(v, w21, o1p_r0);
                    dg0 += 1.0f;                         // uniform on all lanes
                    cn0 += (tgt > 0.5f) ? 1.0f : 0.0f;
                }
            }

            while (m1) {
                const int src = __builtin_ctzll(m1);
                m1 &= (m1 - 1);
                const int bj = (jj << 6) + src;
                const float2 q0 = raw2[bj * 5 + 0];
                const float2 q1 = raw2[bj * 5 + 1];
                const float2 q2 = raw2[bj * 5 + 2];
                const float2 q3 = raw2[bj * 5 + 3];
                const float2 q4 = raw2[bj * 5 + 4];
                const float bx = q0.x - pi1.x;
                const float by = q0.y - pi1.y;
                const float d2 =
                    __fadd_rn(__fadd_rn(__fmul_rn(bx, bx), __fmul_rn(by, by)), EPS);
                const float dist = __fsqrt_rn(d2);
                if (dist < RADIUS) {
                    const float tgt = q2.x;
                    float v = b1h;
                    v = fmaf(q0.x, w1c[0], v);  v = fmaf(q0.y, w1c[1], v);
                    v = fmaf(q1.x, w1c[2], v);  v = fmaf(q1.y, w1c[3], v);
                    v = fmaf(q2.x, w1c[4], v);  v = fmaf(q2.y, w1c[5], v);
                    v = fmaf(q3.x, w1c[6], v);  v = fmaf(q3.y, w1c[7], v);
                    v = fmaf(q4.x, w1c[8], v);  v = fmaf(q4.y, w1c[9], v);
                    v = fmaf(tgt,  w1t, v);
                    v = fmaf(by,   w1y, v);
                    v = fmaf(bx,   w1x, v);
                    v = fmaf(dist, w1d, v);
                    v = fmaxf(v, 0.0f);
                    o0p_r1 = fmaf(v, w20, o0p_r1);
                    o1p_r1 = fmaf(v, w21, o1p_r1);
                    dg1 += 1.0f;
                    cn1 += (tgt > 0.5f) ? 1.0f : 0.0f;
                }
            }
        }
    }

    // 4-step reduce within 16-lane groups: replica groups are bit-identical,
    // so this equals the full 16-slice h-sum exactly (no x0.25 needed).
#pragma unroll
    for (int mm = 1; mm < 16; mm <<= 1) {
        o0p_r0 += __shfl_xor(o0p_r0, mm, 64);
        o1p_r0 += __shfl_xor(o1p_r0, mm, 64);
        o0p_r1 += __shfl_xor(o0p_r1, mm, 64);
        o1p_r1 += __shfl_xor(o1p_r1, mm, 64);
    }

    // lanes 0 and 1 each finalize one row
    if (sub < 2) {
        const int iu = sub ? iu1 : iu0;
        const float2 pi = sub ? pi1 : pi0;
        const float o0p = sub ? o0p_r1 : o0p_r0;
        const float o1p = sub ? o1p_r1 : o1p_r0;
        const float deg = sub ? dg1 : dg0;
        const float cn  = sub ? cn1 : cn0;

        const float2 q1 = raw2[iu * 5 + 1];   // vel
        const float2 q2 = raw2[iu * 5 + 2];   // typ, c5
        const float2 q3 = raw2[iu * 5 + 3];   // c6, c7
        const float2 q4 = raw2[iu * 5 + 4];   // c8, c9

        const float typ_i = q2.x;
        const bool is_cell = typ_i > 0.5f;

        float o0 = deg * b2[0] + o0p;
        float o1 = deg * b2[1] + o1p;
        if (!is_cell) { o0 = 0.0f; o1 = 0.0f; }

        float nvx = q1.x, nvy = q1.y;
        float npx = pi.x, npy = pi.y;
        if (is_cell) {
            nvx = fminf(fmaxf(q1.x + o0 * ACCEL_SCALE, -MAX_VEL), MAX_VEL);
            nvy = fminf(fmaxf(q1.y + o1 * ACCEL_SCALE, -MAX_VEL), MAX_VEL);
            npx = fminf(fmaxf(pi.x + nvx, -MAX_POS), MAX_POS);
            npy = fminf(fmaxf(pi.y + nvy, -MAX_POS), MAX_POS);
        }

        const bool dead     = is_cell && (deg < 3.0f);
        const bool consumed = (!is_cell) && (cn >= 1.0f);
        const float keep = (dead || consumed) ? 0.0f : 1.0f;

        float2* __restrict__ op2 = (float2*)(out + ((size_t)b * NN + iu) * CC);
        op2[0] = make_float2(npx * keep, npy * keep);
        op2[1] = make_float2(nvx * keep, nvy * keep);
        op2[2] = make_float2(typ_i * keep, q2.y * keep);
        op2[3] = make_float2(q3.x * keep, q3.y * keep);
        op2[4] = make_float2(q4.x * keep, q4.y * keep);
    }
}

}  // namespace

extern "C" void kernel_launch(void* const* d_in, const int* in_sizes, int n_in,
                              void* d_out, int out_size, void* d_ws, size_t ws_size,
                              hipStream_t stream) {
    const float* x  = (const float*)d_in[0];
    const float* W1 = (const float*)d_in[1];
    const float* b1 = (const float*)d_in[2];
    const float* W2 = (const float*)d_in[3];
    const float* b2 = (const float*)d_in[4];
    float* out = (float*)d_out;

    gnca_one<<<dim3(BB * 64), dim3(512), 0, stream>>>(x, W1, b1, W2, b2, out);
}